// Round 2
// baseline (1271.822 us; speedup 1.0000x reference)
//
#include <hip/hip_runtime.h>

#define ND 100000
#define DD 128
#define HH 256
#define EE 640000
#define LL 5

// LDS view strides (in elements). 152/280 shorts = 76/140 words == 12 mod 32
#define GS 152   // gather view stride (shorts), 32 rows
#define ZS 280   // z view stride (shorts), 32 rows x 256 cols
#define OS 136   // out-stage bf16 stride (shorts)
#define OF 132   // out-stage fp32 stride (floats)

typedef __attribute__((ext_vector_type(8))) short short8;
typedef __attribute__((ext_vector_type(4))) short short4v;
typedef __attribute__((ext_vector_type(4))) float f32x4;

static __device__ __forceinline__ short f2bf(float f) {
    unsigned u = __builtin_bit_cast(unsigned, f);
    unsigned r = (u + 0x7fffu + ((u >> 16) & 1u)) >> 16;
    return (short)r;
}
static __device__ __forceinline__ float bf2f(short s) {
    unsigned u = ((unsigned)(unsigned short)s) << 16;
    return __builtin_bit_cast(float, u);
}

// ---------------------------------------------------------------------------
// setup: blocks [0,640) fold BN into weights (bf16 [n][k] pack);
//        blocks [640,13140) convert x fp32 -> bf16 into hbufA;
//        blocks [13140,15640) histogram dst degrees (cnt pre-zeroed).
// ---------------------------------------------------------------------------
__global__ __launch_bounds__(256) void setup(
    const float* __restrict__ W1, const float* __restrict__ b1,
    const float* __restrict__ g1, const float* __restrict__ bb1,
    const float* __restrict__ m1, const float* __restrict__ v1,
    const float* __restrict__ W2, const float* __restrict__ b2,
    const float* __restrict__ g2, const float* __restrict__ bb2,
    const float* __restrict__ m2, const float* __restrict__ v2,
    const float* __restrict__ x, const int* __restrict__ dst,
    short* __restrict__ W1p, float* __restrict__ b1e,
    short* __restrict__ W2p, float* __restrict__ b2e,
    short* __restrict__ hb, int* __restrict__ cnt)
{
    int bx = blockIdx.x;
    int tid = threadIdx.x;
    if (bx < 640) {
        int id = bx * 256 + tid;
        if (id < LL * HH * DD) {
            int l = id >> 15;
            int rem = id & 32767;
            {
                int n = rem >> 7, k = rem & 127;
                float s = g1[l * HH + n] * rsqrtf(v1[l * HH + n] + 1e-5f);
                W1p[id] = f2bf(W1[l * 32768 + k * HH + n] * s);
            }
            {
                int n2 = rem >> 8, k2 = rem & 255;
                float s = g2[l * DD + n2] * rsqrtf(v2[l * DD + n2] + 1e-5f);
                W2p[id] = f2bf(W2[l * 32768 + k2 * DD + n2] * s);
            }
        }
        if (id < LL * HH) {
            float s = g1[id] * rsqrtf(v1[id] + 1e-5f);
            b1e[id] = (b1[id] - m1[id]) * s + bb1[id];
        }
        if (id < LL * DD) {
            float s = g2[id] * rsqrtf(v2[id] + 1e-5f);
            b2e[id] = (b2[id] - m2[id]) * s + bb2[id];
        }
    } else if (bx < 13140) {
        int i = (bx - 640) * 256 + tid;          // ND*DD/4 = 3,200,000 float4s
        float4 v = reinterpret_cast<const float4*>(x)[i];
        short4v s;
        s.x = f2bf(v.x); s.y = f2bf(v.y); s.z = f2bf(v.z); s.w = f2bf(v.w);
        reinterpret_cast<short4v*>(hb)[i] = s;
    } else {
        int e = (bx - 13140) * 256 + tid;
        if (e < EE) atomicAdd(&cnt[dst[e]], 1);
    }
}

// per-block inclusive scan of cnt (in place) + block totals + degree histogram
__global__ __launch_bounds__(256) void scan_block(int* __restrict__ cnt, int* __restrict__ bsum,
                                                  int* __restrict__ deghist)
{
    __shared__ int buf[256];
    int tid = threadIdx.x;
    int idx = blockIdx.x * 256 + tid;
    int v = (idx < ND) ? cnt[idx] : 0;
    if (idx < ND) atomicAdd(&deghist[v < 63 ? v : 63], 1);
    buf[tid] = v;
    __syncthreads();
    int sum = v;
    for (int off = 1; off < 256; off <<= 1) {
        int t = (tid >= off) ? buf[tid - off] : 0;
        __syncthreads();
        sum += t;
        buf[tid] = sum;
        __syncthreads();
    }
    if (idx < ND) cnt[idx] = sum;
    if (tid == 255) bsum[blockIdx.x] = sum;
}

// blocks [0,391): exclusive prefix over bsum -> rowst.
// block 391: descending-degree exclusive scan of deghist -> binstart (LPT order).
__global__ __launch_bounds__(256) void apply_offs2(const int* __restrict__ cnt,
                                                   const int* __restrict__ bsum,
                                                   int* __restrict__ rowst,
                                                   const int* __restrict__ deghist,
                                                   int* __restrict__ binstart)
{
    int tid = threadIdx.x;
    if (blockIdx.x == 391) {
        if (tid == 0) {
            int run = 0;
            for (int d = 63; d >= 0; --d) { binstart[d] = run; run += deghist[d]; }
        }
        return;
    }
    __shared__ int sred[256];
    int partial = 0;
    for (int i = tid; i < blockIdx.x; i += 256) partial += bsum[i];
    sred[tid] = partial;
    __syncthreads();
    for (int off = 128; off > 0; off >>= 1) {
        if (tid < off) sred[tid] += sred[tid + off];
        __syncthreads();
    }
    int boff = sred[0];
    int idx = blockIdx.x * 256 + tid;
    if (idx < ND) rowst[idx + 1] = cnt[idx] + boff;
    if (idx == 0) rowst[0] = 0;
}

// blocks [0,2500): CSR fill. blocks [2500,2891): degree-sorted row permutation.
__global__ __launch_bounds__(256) void fill_csr(const int* __restrict__ src,
                                                const int* __restrict__ dst,
                                                const int* __restrict__ rowstart,
                                                int* __restrict__ cursor,
                                                int* __restrict__ csr,
                                                const int* __restrict__ binstart,
                                                int* __restrict__ bincur,
                                                int* __restrict__ perm)
{
    int bx = blockIdx.x;
    if (bx < 2500) {
        int e = bx * 256 + threadIdx.x;
        if (e < EE) {
            int d = dst[e];
            int p = atomicAdd(&cursor[d], 1);
            csr[rowstart[d] + p] = src[e];
        }
    } else {
        int i = (bx - 2500) * 256 + threadIdx.x;
        if (i < ND) {
            int deg = rowstart[i + 1] - rowstart[i];
            if (deg > 63) deg = 63;
            int pos = atomicAdd(&bincur[deg], 1);
            perm[binstart[deg] + pos] = i;
        }
    }
}

// ---------------------------------------------------------------------------
// Fused GIN layer, 512 threads (8 waves) per 32-row block.
//   Rows are degree-sorted (heavy bins first): degree is uniform within a
//   block -> no barrier straggler, wave-coherent gather trip counts.
//   Stage A: flat-issue gather, chunks of 8 independent 16B loads per lane
//            (one vmcnt drain per chunk instead of per 4).
//   GEMM1: wave owns 32 zcols x 32 nodes; W1 fragments pipelined.
//   GEMM2: wave owns 16 outcols x 32 nodes; W2 fragments pipelined.
//   Stage E: LDS bounce -> 256B-contiguous stores to permuted rows (sPerm).
// LDS union: gather stride 152, z stride 280, out stride 136/132 (17,920 B).
// hb_in != hb_out (cross-block WAR hazard).
// ---------------------------------------------------------------------------
__global__ __launch_bounds__(512, 6) void layer_fused(
    const short* __restrict__ hb_in,
    const int* __restrict__ rowst,
    const int* __restrict__ csr,
    const int* __restrict__ perm,
    const short* __restrict__ W1l,    // [256][128] bf16
    const float* __restrict__ b1l,    // [256]
    const short* __restrict__ W2l,    // [128][256] bf16
    const float* __restrict__ b2l,    // [128]
    short* __restrict__ hb_out, float* __restrict__ f_out, int last)
{
    __shared__ __attribute__((aligned(16))) short sU[32 * ZS];   // 17,920 B
    __shared__ int sPerm[32];

    const int tid = threadIdx.x;
    const int r0 = blockIdx.x * 32;          // 3125 * 32 = 100,000 exactly
    const int w = tid >> 6;
    const int lane = tid & 63;
    const int quad = lane >> 4;
    const int l16 = lane & 15;

    // ---- Stage A: degree-uniform flat-issue gather ----
    {
        const int row = tid >> 4;            // 0..31
        const int ch = (tid & 15) * 8;       // 0,8,...,120
        const int grow = perm[r0 + row];
        if ((tid & 15) == 0) sPerm[row] = grow;
        const int s = rowst[grow], e = rowst[grow + 1];
        short8 h0 = *reinterpret_cast<const short8*>(&hb_in[(size_t)grow * DD + ch]);
        float acc[8];
        #pragma unroll
        for (int j = 0; j < 8; ++j) acc[j] = bf2f(h0[j]);

        int i = s;
        int deg = e - s;
        while (deg > 0) {
            int c = deg < 8 ? deg : 8;
            short8 a[8];
            #pragma unroll
            for (int k = 0; k < 8; ++k)
                if (k < c)
                    a[k] = *reinterpret_cast<const short8*>(&hb_in[(size_t)csr[i + k] * DD + ch]);
            #pragma unroll
            for (int k = 0; k < 8; ++k)
                if (k < c) {
                    #pragma unroll
                    for (int j = 0; j < 8; ++j) acc[j] += bf2f(a[k][j]);
                }
            i += c; deg -= c;
        }
        short8 o;
        #pragma unroll
        for (int j = 0; j < 8; ++j) o[j] = f2bf(acc[j]);
        *reinterpret_cast<short8*>(&sU[row * GS + ch]) = o;
    }
    __syncthreads();

    // ---- GEMM1' zT = W1(A) x agg(B): wave owns zcols [w*32, w*32+32) x 32 nodes ----
    const f32x4 zero4 = {0.f, 0.f, 0.f, 0.f};
    f32x4 acc1[2][2];
    #pragma unroll
    for (int h = 0; h < 2; ++h)
        #pragma unroll
        for (int nt = 0; nt < 2; ++nt) acc1[h][nt] = zero4;

    const int zr0 = w * 32 + l16;
    short8 a_cur0 = *reinterpret_cast<const short8*>(&W1l[zr0 * DD + quad * 8]);
    short8 a_cur1 = *reinterpret_cast<const short8*>(&W1l[(zr0 + 16) * DD + quad * 8]);

    __builtin_amdgcn_s_setprio(1);
    #pragma unroll
    for (int ks = 0; ks < 4; ++ks) {
        short8 a_n0, a_n1;
        if (ks < 3) {
            a_n0 = *reinterpret_cast<const short8*>(&W1l[zr0 * DD + (ks + 1) * 32 + quad * 8]);
            a_n1 = *reinterpret_cast<const short8*>(&W1l[(zr0 + 16) * DD + (ks + 1) * 32 + quad * 8]);
        }
        int kofs = ks * 32 + quad * 8;
        short8 b0 = *reinterpret_cast<const short8*>(&sU[l16 * GS + kofs]);
        short8 b1 = *reinterpret_cast<const short8*>(&sU[(16 + l16) * GS + kofs]);
        acc1[0][0] = __builtin_amdgcn_mfma_f32_16x16x32_bf16(a_cur0, b0, acc1[0][0], 0, 0, 0);
        acc1[0][1] = __builtin_amdgcn_mfma_f32_16x16x32_bf16(a_cur0, b1, acc1[0][1], 0, 0, 0);
        acc1[1][0] = __builtin_amdgcn_mfma_f32_16x16x32_bf16(a_cur1, b0, acc1[1][0], 0, 0, 0);
        acc1[1][1] = __builtin_amdgcn_mfma_f32_16x16x32_bf16(a_cur1, b1, acc1[1][1], 0, 0, 0);
        a_cur0 = a_n0; a_cur1 = a_n1;
    }
    __builtin_amdgcn_s_setprio(0);

    float4 bi0 = *reinterpret_cast<const float4*>(&b1l[w * 32 + quad * 4]);
    float4 bi1 = *reinterpret_cast<const float4*>(&b1l[w * 32 + 16 + quad * 4]);
    __syncthreads();   // gather view dead; z view reuses LDS

    // ---- Stage C: bias + ReLU -> sU[node][zcol] (stride ZS), 8B writes ----
    #pragma unroll
    for (int h = 0; h < 2; ++h) {
        float4 bi = h ? bi1 : bi0;
        int zc = w * 32 + h * 16 + quad * 4;
        #pragma unroll
        for (int nt = 0; nt < 2; ++nt) {
            int node = nt * 16 + l16;
            short4v o;
            o.x = f2bf(fmaxf(acc1[h][nt][0] + bi.x, 0.f));
            o.y = f2bf(fmaxf(acc1[h][nt][1] + bi.y, 0.f));
            o.z = f2bf(fmaxf(acc1[h][nt][2] + bi.z, 0.f));
            o.w = f2bf(fmaxf(acc1[h][nt][3] + bi.w, 0.f));
            *reinterpret_cast<short4v*>(&sU[node * ZS + zc]) = o;
        }
    }

    // Preload GEMM2 first weight fragment + bias while barrier settles
    const int orow = w * 16 + l16;
    short8 w_cur = *reinterpret_cast<const short8*>(&W2l[orow * HH + quad * 8]);
    float4 bi2 = *reinterpret_cast<const float4*>(&b2l[w * 16 + quad * 4]);
    __syncthreads();

    // ---- GEMM2' hT = W2(A) x z(B): wave owns outcols [w*16,+16) x 32 nodes ----
    f32x4 acc2[2];
    acc2[0] = zero4; acc2[1] = zero4;

    __builtin_amdgcn_s_setprio(1);
    #pragma unroll
    for (int ks = 0; ks < 8; ++ks) {
        short8 w_next;
        if (ks < 7)
            w_next = *reinterpret_cast<const short8*>(&W2l[orow * HH + (ks + 1) * 32 + quad * 8]);
        int kofs = ks * 32 + quad * 8;
        short8 b0 = *reinterpret_cast<const short8*>(&sU[l16 * ZS + kofs]);
        short8 b1 = *reinterpret_cast<const short8*>(&sU[(16 + l16) * ZS + kofs]);
        acc2[0] = __builtin_amdgcn_mfma_f32_16x16x32_bf16(w_cur, b0, acc2[0], 0, 0, 0);
        acc2[1] = __builtin_amdgcn_mfma_f32_16x16x32_bf16(w_cur, b1, acc2[1], 0, 0, 0);
        w_cur = w_next;
    }
    __builtin_amdgcn_s_setprio(0);
    __syncthreads();   // z view dead; out-stage view reuses LDS

    // ---- Stage E: bias (+ReLU) -> LDS bounce -> 256B-contiguous permuted stores ----
    const int oc = w * 16 + quad * 4;
    if (!last) {
        #pragma unroll
        for (int nt = 0; nt < 2; ++nt) {
            int node = nt * 16 + l16;
            short4v o;
            o.x = f2bf(fmaxf(acc2[nt][0] + bi2.x, 0.f));
            o.y = f2bf(fmaxf(acc2[nt][1] + bi2.y, 0.f));
            o.z = f2bf(fmaxf(acc2[nt][2] + bi2.z, 0.f));
            o.w = f2bf(fmaxf(acc2[nt][3] + bi2.w, 0.f));
            *reinterpret_cast<short4v*>(&sU[node * OS + oc]) = o;
        }
        __syncthreads();
        int row = tid >> 4;
        int c8 = (tid & 15) * 8;
        short8 v = *reinterpret_cast<const short8*>(&sU[row * OS + c8]);
        *reinterpret_cast<short8*>(&hb_out[(size_t)sPerm[row] * DD + c8]) = v;
    } else {
        float* fU = reinterpret_cast<float*>(sU);
        #pragma unroll
        for (int nt = 0; nt < 2; ++nt) {
            int node = nt * 16 + l16;
            float4 o;
            o.x = acc2[nt][0] + bi2.x;
            o.y = acc2[nt][1] + bi2.y;
            o.z = acc2[nt][2] + bi2.z;
            o.w = acc2[nt][3] + bi2.w;
            *reinterpret_cast<float4*>(&fU[node * OF + oc]) = o;
        }
        __syncthreads();
        int row = tid >> 4;
        int cb = (tid & 15) * 8;
        float4 v0 = *reinterpret_cast<const float4*>(&fU[row * OF + cb]);
        float4 v1 = *reinterpret_cast<const float4*>(&fU[row * OF + cb + 4]);
        float* orow_p = &f_out[(size_t)sPerm[row] * DD + cb];
        *reinterpret_cast<float4*>(orow_p) = v0;
        *reinterpret_cast<float4*>(orow_p + 4) = v1;
    }
}

extern "C" void kernel_launch(void* const* d_in, const int* in_sizes, int n_in,
                              void* d_out, int out_size, void* d_ws, size_t ws_size,
                              hipStream_t stream)
{
    const float* x  = (const float*)d_in[0];
    const int* ei   = (const int*)d_in[1];
    const int* src  = ei;
    const int* dst  = ei + EE;
    const float* W1 = (const float*)d_in[2];
    const float* b1 = (const float*)d_in[3];
    const float* g1 = (const float*)d_in[4];
    const float* bb1= (const float*)d_in[5];
    const float* m1 = (const float*)d_in[6];
    const float* v1 = (const float*)d_in[7];
    const float* W2 = (const float*)d_in[8];
    const float* b2 = (const float*)d_in[9];
    const float* g2 = (const float*)d_in[10];
    const float* bb2= (const float*)d_in[11];
    const float* m2 = (const float*)d_in[12];
    const float* v2 = (const float*)d_in[13];

    char* w = (char*)d_ws;
    short* hbufA = (short*)w;                                 // 25,600,000
    short* hbufB = (short*)(w + 25600000);                    // 25,600,000
    short* W1p   = (short*)(w + 51200000);                    //    327,680
    short* W2p   = (short*)(w + 51527680);                    //    327,680
    float* b1e   = (float*)(w + 51855360);                    //      5,120
    float* b2e   = (float*)(w + 51860480);                    //      2,560
    int*   cnt   = (int*)  (w + 51863040);                    //    400,000
    int*   cursor= (int*)  (w + 52263040);                    //    400,000
    int*   deghist=(int*)  (w + 52663040);                    //        256
    int*   bincur= (int*)  (w + 52663296);                    //        256
    int*   binst = (int*)  (w + 52663552);                    //        256
    int*   rowst = (int*)  (w + 52663808);                    //    400,032
    int*   csr   = (int*)  (w + 53063840);                    //  2,560,000
    int*   bsum  = (int*)  (w + 55623840);                    //      1,664
    int*   perm  = (int*)  (w + 55625504);                    //    400,000
    float* out   = (float*)d_out;

    // zero cnt + cursor + deghist + bincur (contiguous 800,512 B)
    hipMemsetAsync(cnt, 0, 800512, stream);
    setup<<<15640, 256, 0, stream>>>(W1, b1, g1, bb1, m1, v1,
                                     W2, b2, g2, bb2, m2, v2,
                                     x, dst, W1p, b1e, W2p, b2e, hbufA, cnt);
    scan_block<<<391, 256, 0, stream>>>(cnt, bsum, deghist);
    apply_offs2<<<392, 256, 0, stream>>>(cnt, bsum, rowst, deghist, binst);
    fill_csr<<<2891, 256, 0, stream>>>(src, dst, rowst, cursor, csr, binst, bincur, perm);

    short* hin = hbufA;
    short* hout = hbufB;
    for (int l = 0; l < LL; ++l) {
        layer_fused<<<3125, 512, 0, stream>>>(hin, rowst, csr, perm,
                                              W1p + l * 32768, b1e + l * HH,
                                              W2p + l * 32768, b2e + l * DD,
                                              hout, out, (l == LL - 1) ? 1 : 0);
        short* t = hin; hin = hout; hout = t;
    }
}

// Round 3
// 671.985 us; speedup vs baseline: 1.8926x; 1.8926x over previous
//
#include <hip/hip_runtime.h>

#define ND 100000
#define DD 128
#define HH 256
#define EE 640000
#define LL 5

// LDS view strides (in elements). 152/280 shorts = 76/140 words == 12 mod 32
#define GS 152   // gather view stride (shorts), 32 rows
#define ZS 280   // z view stride (shorts), 32 rows x 256 cols
#define OS 136   // out-stage bf16 stride (shorts)

typedef __attribute__((ext_vector_type(8))) short short8;
typedef __attribute__((ext_vector_type(4))) short short4v;
typedef __attribute__((ext_vector_type(4))) float f32x4;

static __device__ __forceinline__ short f2bf(float f) {
    unsigned u = __builtin_bit_cast(unsigned, f);
    unsigned r = (u + 0x7fffu + ((u >> 16) & 1u)) >> 16;
    return (short)r;
}
static __device__ __forceinline__ float bf2f(short s) {
    unsigned u = ((unsigned)(unsigned short)s) << 16;
    return __builtin_bit_cast(float, u);
}

// ---------------------------------------------------------------------------
// setup: blocks [0,640) fold BN into weights (bf16 [n][k] pack);
//        blocks [640,13140) convert x fp32 -> bf16 into hbufA;
//        blocks [13140,15640) histogram dst degrees (cnt pre-zeroed).
// ---------------------------------------------------------------------------
__global__ __launch_bounds__(256) void setup(
    const float* __restrict__ W1, const float* __restrict__ b1,
    const float* __restrict__ g1, const float* __restrict__ bb1,
    const float* __restrict__ m1, const float* __restrict__ v1,
    const float* __restrict__ W2, const float* __restrict__ b2,
    const float* __restrict__ g2, const float* __restrict__ bb2,
    const float* __restrict__ m2, const float* __restrict__ v2,
    const float* __restrict__ x, const int* __restrict__ dst,
    short* __restrict__ W1p, float* __restrict__ b1e,
    short* __restrict__ W2p, float* __restrict__ b2e,
    short* __restrict__ hb, int* __restrict__ cnt)
{
    int bx = blockIdx.x;
    int tid = threadIdx.x;
    if (bx < 640) {
        int id = bx * 256 + tid;
        if (id < LL * HH * DD) {
            int l = id >> 15;
            int rem = id & 32767;
            {
                int n = rem >> 7, k = rem & 127;
                float s = g1[l * HH + n] * rsqrtf(v1[l * HH + n] + 1e-5f);
                W1p[id] = f2bf(W1[l * 32768 + k * HH + n] * s);
            }
            {
                int n2 = rem >> 8, k2 = rem & 255;
                float s = g2[l * DD + n2] * rsqrtf(v2[l * DD + n2] + 1e-5f);
                W2p[id] = f2bf(W2[l * 32768 + k2 * DD + n2] * s);
            }
        }
        if (id < LL * HH) {
            float s = g1[id] * rsqrtf(v1[id] + 1e-5f);
            b1e[id] = (b1[id] - m1[id]) * s + bb1[id];
        }
        if (id < LL * DD) {
            float s = g2[id] * rsqrtf(v2[id] + 1e-5f);
            b2e[id] = (b2[id] - m2[id]) * s + bb2[id];
        }
    } else if (bx < 13140) {
        int i = (bx - 640) * 256 + tid;          // ND*DD/4 = 3,200,000 float4s
        float4 v = reinterpret_cast<const float4*>(x)[i];
        short4v s;
        s.x = f2bf(v.x); s.y = f2bf(v.y); s.z = f2bf(v.z); s.w = f2bf(v.w);
        reinterpret_cast<short4v*>(hb)[i] = s;
    } else {
        int e = (bx - 13140) * 256 + tid;
        if (e < EE) atomicAdd(&cnt[dst[e]], 1);
    }
}

// per-block inclusive scan of cnt (in place) + block totals
__global__ __launch_bounds__(256) void scan_block(int* __restrict__ cnt, int* __restrict__ bsum)
{
    __shared__ int buf[256];
    int tid = threadIdx.x;
    int idx = blockIdx.x * 256 + tid;
    int v = (idx < ND) ? cnt[idx] : 0;
    buf[tid] = v;
    __syncthreads();
    int sum = v;
    for (int off = 1; off < 256; off <<= 1) {
        int t = (tid >= off) ? buf[tid - off] : 0;
        __syncthreads();
        sum += t;
        buf[tid] = sum;
        __syncthreads();
    }
    if (idx < ND) cnt[idx] = sum;
    if (tid == 255) bsum[blockIdx.x] = sum;
}

// merged: each block computes its exclusive prefix over bsum, then rowst
__global__ __launch_bounds__(256) void apply_offs2(const int* __restrict__ cnt,
                                                   const int* __restrict__ bsum,
                                                   int* __restrict__ rowst)
{
    __shared__ int sred[256];
    int tid = threadIdx.x;
    int partial = 0;
    for (int i = tid; i < blockIdx.x; i += 256) partial += bsum[i];
    sred[tid] = partial;
    __syncthreads();
    for (int off = 128; off > 0; off >>= 1) {
        if (tid < off) sred[tid] += sred[tid + off];
        __syncthreads();
    }
    int boff = sred[0];
    int idx = blockIdx.x * 256 + tid;
    if (idx < ND) rowst[idx + 1] = cnt[idx] + boff;
    if (idx == 0) rowst[0] = 0;
}

__global__ __launch_bounds__(256) void fill_csr(const int* __restrict__ src,
                                                const int* __restrict__ dst,
                                                const int* __restrict__ rowstart,
                                                int* __restrict__ cursor,
                                                int* __restrict__ csr)
{
    int e = blockIdx.x * 256 + threadIdx.x;
    if (e < EE) {
        int d = dst[e];
        int p = atomicAdd(&cursor[d], 1);
        csr[rowstart[d] + p] = src[e];
    }
}

// ---------------------------------------------------------------------------
// Per-tile MLP (GEMM1 -> bias/ReLU -> GEMM2 -> bias(+ReLU) -> store).
// sG: gather view (32 rows x 128, stride GS). sZ: z view (32 x 256, stride ZS).
// Out-bounce (bf16 path) reuses the sG region (stride OS) — safe: all waves
// are past GEMM1's sG reads at the pre-stageC barrier.
// ---------------------------------------------------------------------------
static __device__ __forceinline__ void tile_mlp(
    const short* __restrict__ sG, short* __restrict__ sZ, short* __restrict__ sO,
    int r0t, int tid,
    const short* __restrict__ W1l, const float* __restrict__ b1l,
    const short* __restrict__ W2l, const float* __restrict__ b2l,
    short* __restrict__ hb_out, float* __restrict__ f_out, int last)
{
    const int w = tid >> 6;
    const int lane = tid & 63;
    const int quad = lane >> 4;
    const int l16 = lane & 15;
    const f32x4 zero4 = {0.f, 0.f, 0.f, 0.f};

    // ---- GEMM1' zT = W1(A) x agg(B): wave owns zcols [w*32, +32) x 32 nodes ----
    f32x4 acc1[2][2];
    #pragma unroll
    for (int h = 0; h < 2; ++h)
        #pragma unroll
        for (int nt = 0; nt < 2; ++nt) acc1[h][nt] = zero4;

    const int zr0 = w * 32 + l16;
    short8 a_cur0 = *reinterpret_cast<const short8*>(&W1l[zr0 * DD + quad * 8]);
    short8 a_cur1 = *reinterpret_cast<const short8*>(&W1l[(zr0 + 16) * DD + quad * 8]);

    __builtin_amdgcn_s_setprio(1);
    #pragma unroll
    for (int ks = 0; ks < 4; ++ks) {
        short8 a_n0, a_n1;
        if (ks < 3) {
            a_n0 = *reinterpret_cast<const short8*>(&W1l[zr0 * DD + (ks + 1) * 32 + quad * 8]);
            a_n1 = *reinterpret_cast<const short8*>(&W1l[(zr0 + 16) * DD + (ks + 1) * 32 + quad * 8]);
        }
        int kofs = ks * 32 + quad * 8;
        short8 b0 = *reinterpret_cast<const short8*>(&sG[l16 * GS + kofs]);
        short8 b1 = *reinterpret_cast<const short8*>(&sG[(16 + l16) * GS + kofs]);
        acc1[0][0] = __builtin_amdgcn_mfma_f32_16x16x32_bf16(a_cur0, b0, acc1[0][0], 0, 0, 0);
        acc1[0][1] = __builtin_amdgcn_mfma_f32_16x16x32_bf16(a_cur0, b1, acc1[0][1], 0, 0, 0);
        acc1[1][0] = __builtin_amdgcn_mfma_f32_16x16x32_bf16(a_cur1, b0, acc1[1][0], 0, 0, 0);
        acc1[1][1] = __builtin_amdgcn_mfma_f32_16x16x32_bf16(a_cur1, b1, acc1[1][1], 0, 0, 0);
        a_cur0 = a_n0; a_cur1 = a_n1;
    }
    __builtin_amdgcn_s_setprio(0);

    float4 bi0 = *reinterpret_cast<const float4*>(&b1l[w * 32 + quad * 4]);
    float4 bi1 = *reinterpret_cast<const float4*>(&b1l[w * 32 + 16 + quad * 4]);
    __syncthreads();   // all waves past sG reads (GEMM1) and past previous tile's sZ reads

    // ---- Stage C: bias + ReLU -> sZ[node][zcol] (stride ZS), 8B writes ----
    #pragma unroll
    for (int h = 0; h < 2; ++h) {
        float4 bi = h ? bi1 : bi0;
        int zc = w * 32 + h * 16 + quad * 4;
        #pragma unroll
        for (int nt = 0; nt < 2; ++nt) {
            int node = nt * 16 + l16;
            short4v o;
            o.x = f2bf(fmaxf(acc1[h][nt][0] + bi.x, 0.f));
            o.y = f2bf(fmaxf(acc1[h][nt][1] + bi.y, 0.f));
            o.z = f2bf(fmaxf(acc1[h][nt][2] + bi.z, 0.f));
            o.w = f2bf(fmaxf(acc1[h][nt][3] + bi.w, 0.f));
            *reinterpret_cast<short4v*>(&sZ[node * ZS + zc]) = o;
        }
    }

    // Preload GEMM2 first weight fragment + bias while barrier settles
    const int orow = w * 16 + l16;
    short8 w_cur = *reinterpret_cast<const short8*>(&W2l[orow * HH + quad * 8]);
    float4 bi2 = *reinterpret_cast<const float4*>(&b2l[w * 16 + quad * 4]);
    __syncthreads();

    // ---- GEMM2' hT = W2(A) x z(B): wave owns outcols [w*16,+16) x 32 nodes ----
    f32x4 acc2[2];
    acc2[0] = zero4; acc2[1] = zero4;

    __builtin_amdgcn_s_setprio(1);
    #pragma unroll
    for (int ks = 0; ks < 8; ++ks) {
        short8 w_next;
        if (ks < 7)
            w_next = *reinterpret_cast<const short8*>(&W2l[orow * HH + (ks + 1) * 32 + quad * 8]);
        int kofs = ks * 32 + quad * 8;
        short8 b0 = *reinterpret_cast<const short8*>(&sZ[l16 * ZS + kofs]);
        short8 b1 = *reinterpret_cast<const short8*>(&sZ[(16 + l16) * ZS + kofs]);
        acc2[0] = __builtin_amdgcn_mfma_f32_16x16x32_bf16(w_cur, b0, acc2[0], 0, 0, 0);
        acc2[1] = __builtin_amdgcn_mfma_f32_16x16x32_bf16(w_cur, b1, acc2[1], 0, 0, 0);
        w_cur = w_next;
    }
    __builtin_amdgcn_s_setprio(0);

    // ---- Stage E ----
    const int oc = w * 16 + quad * 4;
    if (!last) {
        // bias+ReLU -> out-bounce in sO (= this tile's gather region), 16B stores
        #pragma unroll
        for (int nt = 0; nt < 2; ++nt) {
            int node = nt * 16 + l16;
            short4v o;
            o.x = f2bf(fmaxf(acc2[nt][0] + bi2.x, 0.f));
            o.y = f2bf(fmaxf(acc2[nt][1] + bi2.y, 0.f));
            o.z = f2bf(fmaxf(acc2[nt][2] + bi2.z, 0.f));
            o.w = f2bf(fmaxf(acc2[nt][3] + bi2.w, 0.f));
            *reinterpret_cast<short4v*>(&sO[node * OS + oc]) = o;
        }
        __syncthreads();
        int row = tid >> 4;
        int c8 = (tid & 15) * 8;
        if (r0t + row < ND) {
            short8 v = *reinterpret_cast<const short8*>(&sO[row * OS + c8]);
            *reinterpret_cast<short8*>(&hb_out[(size_t)(r0t + row) * DD + c8]) = v;
        }
    } else {
        // last layer: direct fp32 stores (no ReLU)
        #pragma unroll
        for (int nt = 0; nt < 2; ++nt) {
            int node = r0t + nt * 16 + l16;
            if (node < ND) {
                float4 o;
                o.x = acc2[nt][0] + bi2.x;
                o.y = acc2[nt][1] + bi2.y;
                o.z = acc2[nt][2] + bi2.z;
                o.w = acc2[nt][3] + bi2.w;
                *reinterpret_cast<float4*>(&f_out[(size_t)node * DD + oc]) = o;
            }
        }
    }
}

// ---------------------------------------------------------------------------
// Fused GIN layer, 512 threads (8 waves) per block, TWO 32-row tiles per block.
//   Stage A: both tiles' gathers interleaved flat — every lane runs two
//            independent csr->row dependency chains with 8 x 16B loads in
//            flight (2x the MLP of the single-tile version).
//   Then tile_mlp(T0), tile_mlp(T1) back-to-back sharing one z buffer.
// LDS: gA 9,728 + gB 9,728 + z 17,920 = 37,376 B. VGPR target <=128
// (launch_bounds(512,4)) -> 2 blocks/CU; explicit ILP replaces lost TLP.
// hb_in != hb_out (cross-block WAR hazard).
// ---------------------------------------------------------------------------
__global__ __launch_bounds__(512, 4) void layer_fused(
    const short* __restrict__ hb_in,
    const int* __restrict__ rowst,
    const int* __restrict__ csr,
    const short* __restrict__ W1l,    // [256][128] bf16
    const float* __restrict__ b1l,    // [256]
    const short* __restrict__ W2l,    // [128][256] bf16
    const float* __restrict__ b2l,    // [128]
    short* __restrict__ hb_out, float* __restrict__ f_out, int last)
{
    __shared__ __attribute__((aligned(16))) short sGA[32 * GS];
    __shared__ __attribute__((aligned(16))) short sGB[32 * GS];
    __shared__ __attribute__((aligned(16))) short sZ[32 * ZS];

    const int tid = threadIdx.x;
    const int r0 = blockIdx.x * 64;          // 1563 * 64 = 100,032 (guarded)

    // ---- Stage A: dual-tile interleaved gather ----
    {
        const int row = tid >> 4;            // 0..31
        const int ch = (tid & 15) * 8;       // 0,8,...,120
        const int rA = r0 + row;
        const int rB = r0 + 32 + row;

        int sA = 0, dA = 0, sB = 0, dB = 0;
        if (rA < ND) { sA = rowst[rA]; dA = rowst[rA + 1] - sA; }
        if (rB < ND) { sB = rowst[rB]; dB = rowst[rB + 1] - sB; }

        float accA[8], accB[8];
        {
            short8 hA, hB;
            if (rA < ND) hA = *reinterpret_cast<const short8*>(&hb_in[(size_t)rA * DD + ch]);
            if (rB < ND) hB = *reinterpret_cast<const short8*>(&hb_in[(size_t)rB * DD + ch]);
            #pragma unroll
            for (int j = 0; j < 8; ++j) accA[j] = (rA < ND) ? bf2f(hA[j]) : 0.f;
            #pragma unroll
            for (int j = 0; j < 8; ++j) accB[j] = (rB < ND) ? bf2f(hB[j]) : 0.f;
        }

        int iA = sA, iB = sB;
        while (dA > 0 || dB > 0) {
            int cA = dA < 4 ? dA : 4;
            int cB = dB < 4 ? dB : 4;
            short8 a[4], b[4];
            #pragma unroll
            for (int k = 0; k < 4; ++k)
                if (k < cA)
                    a[k] = *reinterpret_cast<const short8*>(&hb_in[(size_t)csr[iA + k] * DD + ch]);
            #pragma unroll
            for (int k = 0; k < 4; ++k)
                if (k < cB)
                    b[k] = *reinterpret_cast<const short8*>(&hb_in[(size_t)csr[iB + k] * DD + ch]);
            #pragma unroll
            for (int k = 0; k < 4; ++k)
                if (k < cA) {
                    #pragma unroll
                    for (int j = 0; j < 8; ++j) accA[j] += bf2f(a[k][j]);
                }
            #pragma unroll
            for (int k = 0; k < 4; ++k)
                if (k < cB) {
                    #pragma unroll
                    for (int j = 0; j < 8; ++j) accB[j] += bf2f(b[k][j]);
                }
            iA += cA; dA -= cA;
            iB += cB; dB -= cB;
        }
        short8 oA, oB;
        #pragma unroll
        for (int j = 0; j < 8; ++j) oA[j] = f2bf(accA[j]);
        #pragma unroll
        for (int j = 0; j < 8; ++j) oB[j] = f2bf(accB[j]);
        *reinterpret_cast<short8*>(&sGA[row * GS + ch]) = oA;
        *reinterpret_cast<short8*>(&sGB[row * GS + ch]) = oB;
    }
    __syncthreads();

    tile_mlp(sGA, sZ, sGA, r0,      tid, W1l, b1l, W2l, b2l, hb_out, f_out, last);
    tile_mlp(sGB, sZ, sGB, r0 + 32, tid, W1l, b1l, W2l, b2l, hb_out, f_out, last);
}

extern "C" void kernel_launch(void* const* d_in, const int* in_sizes, int n_in,
                              void* d_out, int out_size, void* d_ws, size_t ws_size,
                              hipStream_t stream)
{
    const float* x  = (const float*)d_in[0];
    const int* ei   = (const int*)d_in[1];
    const int* src  = ei;
    const int* dst  = ei + EE;
    const float* W1 = (const float*)d_in[2];
    const float* b1 = (const float*)d_in[3];
    const float* g1 = (const float*)d_in[4];
    const float* bb1= (const float*)d_in[5];
    const float* m1 = (const float*)d_in[6];
    const float* v1 = (const float*)d_in[7];
    const float* W2 = (const float*)d_in[8];
    const float* b2 = (const float*)d_in[9];
    const float* g2 = (const float*)d_in[10];
    const float* bb2= (const float*)d_in[11];
    const float* m2 = (const float*)d_in[12];
    const float* v2 = (const float*)d_in[13];

    char* w = (char*)d_ws;
    short* hbufA = (short*)w;                                 // 25,600,000
    short* hbufB = (short*)(w + 25600000);                    // 25,600,000
    short* W1p   = (short*)(w + 51200000);                    //    327,680
    short* W2p   = (short*)(w + 51527680);                    //    327,680
    float* b1e   = (float*)(w + 51855360);                    //      5,120
    float* b2e   = (float*)(w + 51860480);                    //      2,560
    int*   cnt   = (int*)  (w + 51863040);                    //    400,000
    int*   cursor= (int*)  (w + 52263040);                    //    400,000 (contiguous after cnt)
    int*   rowst = (int*)  (w + 52663040);                    //    400,032
    int*   csr   = (int*)  (w + 53063072);                    //  2,560,000
    int*   bsum  = (int*)  (w + 55623072);                    //      1,664
    float* out   = (float*)d_out;

    // zero cnt + cursor (contiguous 800,000 B) — capture-safe async memset
    hipMemsetAsync(cnt, 0, 800000, stream);
    setup<<<15640, 256, 0, stream>>>(W1, b1, g1, bb1, m1, v1,
                                     W2, b2, g2, bb2, m2, v2,
                                     x, dst, W1p, b1e, W2p, b2e, hbufA, cnt);
    scan_block<<<391, 256, 0, stream>>>(cnt, bsum);
    apply_offs2<<<391, 256, 0, stream>>>(cnt, bsum, rowst);
    fill_csr<<<2500, 256, 0, stream>>>(src, dst, rowst, cursor, csr);

    short* hin = hbufA;
    short* hout = hbufB;
    for (int l = 0; l < LL; ++l) {
        layer_fused<<<1563, 512, 0, stream>>>(hin, rowst, csr,
                                              W1p + l * 32768, b1e + l * HH,
                                              W2p + l * 32768, b2e + l * DD,
                                              hout, out, (l == LL - 1) ? 1 : 0);
        short* t = hin; hin = hout; hout = t;
    }
}

// Round 5
// 547.627 us; speedup vs baseline: 2.3224x; 1.2271x over previous
//
#include <hip/hip_runtime.h>

#define ND 100000
#define DD 128
#define HH 256
#define EE 640000
#define LL 5

// LDS view strides (in elements, fp16). 152/280 shorts = 76/140 words == 12 mod 32
// -> measured (R1) bank-conflict reduction 3.6M -> 2.8M vs 136/264.
#define GS 152   // gather view stride, 64 rows x 128 cols
#define ZS 280   // z view stride, 64 rows x 256 cols

typedef __attribute__((ext_vector_type(8))) short short8;
typedef __attribute__((ext_vector_type(4))) short short4v;
typedef __attribute__((ext_vector_type(4))) float f32x4;
typedef __attribute__((ext_vector_type(8))) _Float16 half8;
typedef __attribute__((ext_vector_type(4))) _Float16 half4;
typedef __attribute__((ext_vector_type(2))) _Float16 half2v;

static __device__ __forceinline__ short f2h(float f) {
    return __builtin_bit_cast(short, (_Float16)f);
}

// pack two fp32 -> packed fp16 pair (v_cvt_pkrtz_f16_f32, 1 instr)
static __device__ __forceinline__ half2v pk2(float a, float b) {
    return __builtin_bit_cast(half2v, __builtin_amdgcn_cvt_pkrtz(a, b));
}

// ---------------------------------------------------------------------------
// setup: blocks [0,640) fold BN into weights (fp16 [n][k] pack);
//        blocks [640,13140) convert x fp32 -> fp16 into hbufA;
//        blocks [13140,15640) histogram dst degrees (cnt pre-zeroed).
// ---------------------------------------------------------------------------
__global__ __launch_bounds__(256) void setup(
    const float* __restrict__ W1, const float* __restrict__ b1,
    const float* __restrict__ g1, const float* __restrict__ bb1,
    const float* __restrict__ m1, const float* __restrict__ v1,
    const float* __restrict__ W2, const float* __restrict__ b2,
    const float* __restrict__ g2, const float* __restrict__ bb2,
    const float* __restrict__ m2, const float* __restrict__ v2,
    const float* __restrict__ x, const int* __restrict__ dst,
    short* __restrict__ W1p, float* __restrict__ b1e,
    short* __restrict__ W2p, float* __restrict__ b2e,
    short* __restrict__ hb, int* __restrict__ cnt)
{
    int bx = blockIdx.x;
    int tid = threadIdx.x;
    if (bx < 640) {
        int id = bx * 256 + tid;
        if (id < LL * HH * DD) {
            int l = id >> 15;
            int rem = id & 32767;
            {
                int n = rem >> 7, k = rem & 127;
                float s = g1[l * HH + n] * rsqrtf(v1[l * HH + n] + 1e-5f);
                W1p[id] = f2h(W1[l * 32768 + k * HH + n] * s);
            }
            {
                int n2 = rem >> 8, k2 = rem & 255;
                float s = g2[l * DD + n2] * rsqrtf(v2[l * DD + n2] + 1e-5f);
                W2p[id] = f2h(W2[l * 32768 + k2 * DD + n2] * s);
            }
        }
        if (id < LL * HH) {
            float s = g1[id] * rsqrtf(v1[id] + 1e-5f);
            b1e[id] = (b1[id] - m1[id]) * s + bb1[id];
        }
        if (id < LL * DD) {
            float s = g2[id] * rsqrtf(v2[id] + 1e-5f);
            b2e[id] = (b2[id] - m2[id]) * s + bb2[id];
        }
    } else if (bx < 13140) {
        int i = (bx - 640) * 256 + tid;          // ND*DD/4 = 3,200,000 float4s
        float4 v = reinterpret_cast<const float4*>(x)[i];
        half2v p0 = pk2(v.x, v.y);
        half2v p1 = pk2(v.z, v.w);
        half4 hv = __builtin_shufflevector(p0, p1, 0, 1, 2, 3);
        reinterpret_cast<short4v*>(hb)[i] = __builtin_bit_cast(short4v, hv);
    } else {
        int e = (bx - 13140) * 256 + tid;
        if (e < EE) atomicAdd(&cnt[dst[e]], 1);
    }
}

// per-block inclusive scan of cnt (in place) + block totals
__global__ __launch_bounds__(256) void scan_block(int* __restrict__ cnt, int* __restrict__ bsum)
{
    __shared__ int buf[256];
    int tid = threadIdx.x;
    int idx = blockIdx.x * 256 + tid;
    int v = (idx < ND) ? cnt[idx] : 0;
    buf[tid] = v;
    __syncthreads();
    int sum = v;
    for (int off = 1; off < 256; off <<= 1) {
        int t = (tid >= off) ? buf[tid - off] : 0;
        __syncthreads();
        sum += t;
        buf[tid] = sum;
        __syncthreads();
    }
    if (idx < ND) cnt[idx] = sum;
    if (tid == 255) bsum[blockIdx.x] = sum;
}

// merged: each block computes its exclusive prefix over bsum, then rowst
__global__ __launch_bounds__(256) void apply_offs2(const int* __restrict__ cnt,
                                                   const int* __restrict__ bsum,
                                                   int* __restrict__ rowst)
{
    __shared__ int sred[256];
    int tid = threadIdx.x;
    int partial = 0;
    for (int i = tid; i < blockIdx.x; i += 256) partial += bsum[i];
    sred[tid] = partial;
    __syncthreads();
    for (int off = 128; off > 0; off >>= 1) {
        if (tid < off) sred[tid] += sred[tid + off];
        __syncthreads();
    }
    int boff = sred[0];
    int idx = blockIdx.x * 256 + tid;
    if (idx < ND) rowst[idx + 1] = cnt[idx] + boff;
    if (idx == 0) rowst[0] = 0;
}

__global__ __launch_bounds__(256) void fill_csr(const int* __restrict__ src,
                                                const int* __restrict__ dst,
                                                const int* __restrict__ rowstart,
                                                int* __restrict__ cursor,
                                                int* __restrict__ csr)
{
    int e = blockIdx.x * 256 + threadIdx.x;
    if (e < EE) {
        int d = dst[e];
        int p = atomicAdd(&cursor[d], 1);
        csr[rowstart[d] + p] = src[e];
    }
}

// ---------------------------------------------------------------------------
// Fused GIN layer, 1024 threads (16 waves) per 64-row block (R0 structure).
//   Stage A: gather, ONE chunk/thread, unroll x4 batched loads; accumulation
//            in PACKED fp16 (v_pk_add_f16): 4 VALU ops per 16B chunk vs 16
//            for the bf16 unpack/add path, and no final repack.
//   GEMM1: wave owns 16 zcols x 64 nodes; W1 fragments preloaded pre-barrier.
//   GEMM2: wave owns 16 outcols x 32 nodes; W2 fragments software-pipelined.
// hb_in != hb_out (cross-block WAR hazard).
// LDS union: gather view stride 152, z view stride 280 (35,840 B).
// ---------------------------------------------------------------------------
__global__ __launch_bounds__(1024, 8) void layer_fused(
    const short* __restrict__ hb_in,
    const int* __restrict__ rowst,
    const int* __restrict__ csr,
    const short* __restrict__ W1l,    // [256][128] fp16
    const float* __restrict__ b1l,    // [256]
    const short* __restrict__ W2l,    // [128][256] fp16
    const float* __restrict__ b2l,    // [128]
    short* __restrict__ hb_out, float* __restrict__ f_out, int last)
{
    __shared__ __attribute__((aligned(16))) short sU[64 * ZS];   // 35,840 B

    const int tid = threadIdx.x;
    const int r0 = blockIdx.x * 64;
    const int wave = tid >> 6;
    const int lane = tid & 63;
    const int quad = lane >> 4;
    const int l16 = lane & 15;

    // Preload GEMM1 weight fragments + bias (independent of gather)
    const int zrow = wave * 16 + l16;
    half8 aw1[4];
    for (int ks = 0; ks < 4; ++ks)
        aw1[ks] = __builtin_bit_cast(half8,
            *reinterpret_cast<const short8*>(&W1l[zrow * DD + ks * 32 + quad * 8]));
    float4 bias1 = *reinterpret_cast<const float4*>(&b1l[wave * 16 + quad * 4]);

    // ---- Stage A: neighbor gather, unroll-4 batched loads, packed-f16 accum ----
    {
        int row = tid >> 4;           // 0..63
        int ch = (tid & 15) * 8;      // 0,8,...,120
        int grow = r0 + row;
        half8 acc = {};
        if (grow < ND) {
            acc = __builtin_bit_cast(half8,
                *reinterpret_cast<const short8*>(&hb_in[(size_t)grow * DD + ch]));
            int s = rowst[grow], e = rowst[grow + 1];
            int i = s;
            for (; i + 3 < e; i += 4) {
                int s0 = csr[i], s1 = csr[i + 1], s2 = csr[i + 2], s3 = csr[i + 3];
                half8 a0 = __builtin_bit_cast(half8,
                    *reinterpret_cast<const short8*>(&hb_in[(size_t)s0 * DD + ch]));
                half8 a1 = __builtin_bit_cast(half8,
                    *reinterpret_cast<const short8*>(&hb_in[(size_t)s1 * DD + ch]));
                half8 a2 = __builtin_bit_cast(half8,
                    *reinterpret_cast<const short8*>(&hb_in[(size_t)s2 * DD + ch]));
                half8 a3 = __builtin_bit_cast(half8,
                    *reinterpret_cast<const short8*>(&hb_in[(size_t)s3 * DD + ch]));
                half8 s01 = a0 + a1;
                half8 s23 = a2 + a3;
                acc = acc + (s01 + s23);
            }
            for (; i < e; ++i) {
                half8 a = __builtin_bit_cast(half8,
                    *reinterpret_cast<const short8*>(&hb_in[(size_t)csr[i] * DD + ch]));
                acc = acc + a;
            }
        }
        *reinterpret_cast<short8*>(&sU[row * GS + ch]) = __builtin_bit_cast(short8, acc);
    }
    __syncthreads();

    // ---- GEMM1' zT = W1(A) x agg(B): wave owns zcols [wave*16,+16) x 64 nodes ----
    const f32x4 zero4 = {0.f, 0.f, 0.f, 0.f};
    f32x4 acc1[4];
    for (int nt = 0; nt < 4; ++nt) acc1[nt] = zero4;

    for (int ks = 0; ks < 4; ++ks) {
        int kofs = ks * 32 + quad * 8;
        for (int nt = 0; nt < 4; ++nt) {
            half8 bn = __builtin_bit_cast(half8,
                *reinterpret_cast<const short8*>(&sU[(nt * 16 + l16) * GS + kofs]));
            acc1[nt] = __builtin_amdgcn_mfma_f32_16x16x32_f16(aw1[ks], bn, acc1[nt], 0, 0, 0);
        }
    }
    __syncthreads();   // gather view dead; z view reuses LDS

    // ---- Stage C: bias + ReLU -> sU[node][zcol] (stride ZS), pk-f16 writes ----
    {
        int zc = wave * 16 + quad * 4;
        for (int nt = 0; nt < 4; ++nt) {
            int node = nt * 16 + l16;
            half2v p0 = pk2(fmaxf(acc1[nt][0] + bias1.x, 0.f),
                            fmaxf(acc1[nt][1] + bias1.y, 0.f));
            half2v p1 = pk2(fmaxf(acc1[nt][2] + bias1.z, 0.f),
                            fmaxf(acc1[nt][3] + bias1.w, 0.f));
            half4 hv = __builtin_shufflevector(p0, p1, 0, 1, 2, 3);
            *reinterpret_cast<short4v*>(&sU[node * ZS + zc]) = __builtin_bit_cast(short4v, hv);
        }
    }

    // Preload GEMM2 first weight fragment + bias while barrier settles
    const int ct16 = wave >> 1;
    const int nh = wave & 1;
    const int orow = ct16 * 16 + l16;
    half8 w_cur = __builtin_bit_cast(half8,
        *reinterpret_cast<const short8*>(&W2l[orow * HH + quad * 8]));
    float4 bias2 = *reinterpret_cast<const float4*>(&b2l[ct16 * 16 + quad * 4]);
    __syncthreads();

    // ---- GEMM2' hT = W2(A) x z(B): wave owns outcols [ct16*16,+16) x 32 nodes,
    //      W2 fragments software-pipelined ----
    f32x4 acc2[2];
    for (int nt = 0; nt < 2; ++nt) acc2[nt] = zero4;

    for (int ks = 0; ks < 8; ++ks) {
        half8 w_next;
        if (ks < 7)
            w_next = __builtin_bit_cast(half8,
                *reinterpret_cast<const short8*>(&W2l[orow * HH + (ks + 1) * 32 + quad * 8]));
        int kofs = ks * 32 + quad * 8;
        for (int nt = 0; nt < 2; ++nt) {
            int node = nh * 32 + nt * 16 + l16;
            half8 bn = __builtin_bit_cast(half8,
                *reinterpret_cast<const short8*>(&sU[node * ZS + kofs]));
            acc2[nt] = __builtin_amdgcn_mfma_f32_16x16x32_f16(w_cur, bn, acc2[nt], 0, 0, 0);
        }
        w_cur = w_next;
    }

    // ---- Stage E: bias (+ReLU) -> vectorized global stores ----
    {
        int oc = ct16 * 16 + quad * 4;
        for (int nt = 0; nt < 2; ++nt) {
            int node = r0 + nh * 32 + nt * 16 + l16;
            if (node < ND) {
                float v0 = acc2[nt][0] + bias2.x;
                float v1 = acc2[nt][1] + bias2.y;
                float v2 = acc2[nt][2] + bias2.z;
                float v3 = acc2[nt][3] + bias2.w;
                if (!last) {
                    half2v p0 = pk2(fmaxf(v0, 0.f), fmaxf(v1, 0.f));
                    half2v p1 = pk2(fmaxf(v2, 0.f), fmaxf(v3, 0.f));
                    half4 hv = __builtin_shufflevector(p0, p1, 0, 1, 2, 3);
                    *reinterpret_cast<short4v*>(&hb_out[(size_t)node * DD + oc]) =
                        __builtin_bit_cast(short4v, hv);
                } else {
                    float4 st; st.x = v0; st.y = v1; st.z = v2; st.w = v3;
                    *reinterpret_cast<float4*>(&f_out[(size_t)node * DD + oc]) = st;
                }
            }
        }
    }
}

extern "C" void kernel_launch(void* const* d_in, const int* in_sizes, int n_in,
                              void* d_out, int out_size, void* d_ws, size_t ws_size,
                              hipStream_t stream)
{
    const float* x  = (const float*)d_in[0];
    const int* ei   = (const int*)d_in[1];
    const int* src  = ei;
    const int* dst  = ei + EE;
    const float* W1 = (const float*)d_in[2];
    const float* b1 = (const float*)d_in[3];
    const float* g1 = (const float*)d_in[4];
    const float* bb1= (const float*)d_in[5];
    const float* m1 = (const float*)d_in[6];
    const float* v1 = (const float*)d_in[7];
    const float* W2 = (const float*)d_in[8];
    const float* b2 = (const float*)d_in[9];
    const float* g2 = (const float*)d_in[10];
    const float* bb2= (const float*)d_in[11];
    const float* m2 = (const float*)d_in[12];
    const float* v2 = (const float*)d_in[13];

    char* w = (char*)d_ws;
    short* hbufA = (short*)w;                                 // 25,600,000
    short* hbufB = (short*)(w + 25600000);                    // 25,600,000
    short* W1p   = (short*)(w + 51200000);                    //    327,680
    short* W2p   = (short*)(w + 51527680);                    //    327,680
    float* b1e   = (float*)(w + 51855360);                    //      5,120
    float* b2e   = (float*)(w + 51860480);                    //      2,560
    int*   cnt   = (int*)  (w + 51863040);                    //    400,000
    int*   cursor= (int*)  (w + 52263040);                    //    400,000 (contiguous after cnt)
    int*   rowst = (int*)  (w + 52663040);                    //    400,032
    int*   csr   = (int*)  (w + 53063072);                    //  2,560,000
    int*   bsum  = (int*)  (w + 55623072);                    //      1,664
    float* out   = (float*)d_out;

    // zero cnt + cursor (contiguous 800,000 B) — capture-safe async memset
    (void)hipMemsetAsync(cnt, 0, 800000, stream);
    setup<<<15640, 256, 0, stream>>>(W1, b1, g1, bb1, m1, v1,
                                     W2, b2, g2, bb2, m2, v2,
                                     x, dst, W1p, b1e, W2p, b2e, hbufA, cnt);
    scan_block<<<391, 256, 0, stream>>>(cnt, bsum);
    apply_offs2<<<391, 256, 0, stream>>>(cnt, bsum, rowst);
    fill_csr<<<2500, 256, 0, stream>>>(src, dst, rowst, cursor, csr);

    short* hin = hbufA;
    short* hout = hbufB;
    for (int l = 0; l < LL; ++l) {
        layer_fused<<<1563, 1024, 0, stream>>>(hin, rowst, csr,
                                               W1p + l * 32768, b1e + l * HH,
                                               W2p + l * 32768, b2e + l * DD,
                                               hout, out, (l == LL - 1) ? 1 : 0);
        short* t = hin; hin = hout; hout = t;
    }
}

// Round 6
// 533.974 us; speedup vs baseline: 2.3818x; 1.0256x over previous
//
#include <hip/hip_runtime.h>

#define ND 100000
#define DD 128
#define HH 256
#define EE 640000
#define LL 5

// LDS view strides (in elements, fp16). 152/280 shorts = 76/140 words == 12 mod 32
#define GS 152   // gather view stride, 64 rows x 128 cols
#define ZS 280   // z view stride, 64 rows x 256 cols

typedef __attribute__((ext_vector_type(8))) short short8;
typedef __attribute__((ext_vector_type(4))) short short4v;
typedef __attribute__((ext_vector_type(4))) float f32x4;
typedef __attribute__((ext_vector_type(8))) _Float16 half8;
typedef __attribute__((ext_vector_type(4))) _Float16 half4;
typedef __attribute__((ext_vector_type(2))) _Float16 half2v;

static __device__ __forceinline__ short f2h(float f) {
    return __builtin_bit_cast(short, (_Float16)f);
}

// pack two fp32 -> packed fp16 pair (v_cvt_pkrtz_f16_f32, 1 instr)
static __device__ __forceinline__ half2v pk2(float a, float b) {
    return __builtin_bit_cast(half2v, __builtin_amdgcn_cvt_pkrtz(a, b));
}

// ---------------------------------------------------------------------------
// setup: blocks [0,640) fold BN into weights (fp16 [n][k] pack);
//        blocks [640,13140) convert x fp32 -> fp16 into hbufA;
//        blocks [13140,15640) histogram dst degrees (cnt pre-zeroed).
// ---------------------------------------------------------------------------
__global__ __launch_bounds__(256) void setup(
    const float* __restrict__ W1, const float* __restrict__ b1,
    const float* __restrict__ g1, const float* __restrict__ bb1,
    const float* __restrict__ m1, const float* __restrict__ v1,
    const float* __restrict__ W2, const float* __restrict__ b2,
    const float* __restrict__ g2, const float* __restrict__ bb2,
    const float* __restrict__ m2, const float* __restrict__ v2,
    const float* __restrict__ x, const int* __restrict__ dst,
    short* __restrict__ W1p, float* __restrict__ b1e,
    short* __restrict__ W2p, float* __restrict__ b2e,
    short* __restrict__ hb, int* __restrict__ cnt)
{
    int bx = blockIdx.x;
    int tid = threadIdx.x;
    if (bx < 640) {
        int id = bx * 256 + tid;
        if (id < LL * HH * DD) {
            int l = id >> 15;
            int rem = id & 32767;
            {
                int n = rem >> 7, k = rem & 127;
                float s = g1[l * HH + n] * rsqrtf(v1[l * HH + n] + 1e-5f);
                W1p[id] = f2h(W1[l * 32768 + k * HH + n] * s);
            }
            {
                int n2 = rem >> 8, k2 = rem & 255;
                float s = g2[l * DD + n2] * rsqrtf(v2[l * DD + n2] + 1e-5f);
                W2p[id] = f2h(W2[l * 32768 + k2 * DD + n2] * s);
            }
        }
        if (id < LL * HH) {
            float s = g1[id] * rsqrtf(v1[id] + 1e-5f);
            b1e[id] = (b1[id] - m1[id]) * s + bb1[id];
        }
        if (id < LL * DD) {
            float s = g2[id] * rsqrtf(v2[id] + 1e-5f);
            b2e[id] = (b2[id] - m2[id]) * s + bb2[id];
        }
    } else if (bx < 13140) {
        int i = (bx - 640) * 256 + tid;          // ND*DD/4 = 3,200,000 float4s
        float4 v = reinterpret_cast<const float4*>(x)[i];
        half2v p0 = pk2(v.x, v.y);
        half2v p1 = pk2(v.z, v.w);
        half4 hv = __builtin_shufflevector(p0, p1, 0, 1, 2, 3);
        reinterpret_cast<short4v*>(hb)[i] = __builtin_bit_cast(short4v, hv);
    } else {
        int e = (bx - 13140) * 256 + tid;
        if (e < EE) atomicAdd(&cnt[dst[e]], 1);
    }
}

// per-block inclusive scan of cnt (in place) + block totals
__global__ __launch_bounds__(256) void scan_block(int* __restrict__ cnt, int* __restrict__ bsum)
{
    __shared__ int buf[256];
    int tid = threadIdx.x;
    int idx = blockIdx.x * 256 + tid;
    int v = (idx < ND) ? cnt[idx] : 0;
    buf[tid] = v;
    __syncthreads();
    int sum = v;
    for (int off = 1; off < 256; off <<= 1) {
        int t = (tid >= off) ? buf[tid - off] : 0;
        __syncthreads();
        sum += t;
        buf[tid] = sum;
        __syncthreads();
    }
    if (idx < ND) cnt[idx] = sum;
    if (tid == 255) bsum[blockIdx.x] = sum;
}

// merged: each block computes its exclusive prefix over bsum, then rowst
__global__ __launch_bounds__(256) void apply_offs2(const int* __restrict__ cnt,
                                                   const int* __restrict__ bsum,
                                                   int* __restrict__ rowst)
{
    __shared__ int sred[256];
    int tid = threadIdx.x;
    int partial = 0;
    for (int i = tid; i < blockIdx.x; i += 256) partial += bsum[i];
    sred[tid] = partial;
    __syncthreads();
    for (int off = 128; off > 0; off >>= 1) {
        if (tid < off) sred[tid] += sred[tid + off];
        __syncthreads();
    }
    int boff = sred[0];
    int idx = blockIdx.x * 256 + tid;
    if (idx < ND) rowst[idx + 1] = cnt[idx] + boff;
    if (idx == 0) rowst[0] = 0;
}

__global__ __launch_bounds__(256) void fill_csr(const int* __restrict__ src,
                                                const int* __restrict__ dst,
                                                const int* __restrict__ rowstart,
                                                int* __restrict__ cursor,
                                                int* __restrict__ csr)
{
    int e = blockIdx.x * 256 + threadIdx.x;
    if (e < EE) {
        int d = dst[e];
        int p = atomicAdd(&cursor[d], 1);
        csr[rowstart[d] + p] = src[e];
    }
}

// ---------------------------------------------------------------------------
// Fused GIN layer, 1024 threads (16 waves) per 64-row block (R0 structure).
//   Stage A: gather. Per 16-lane row-group, csr indices are loaded 16-at-a-
//            time (ONE coalesced load per 16 edges, each lane one index) and
//            distributed from registers via __shfl — the per-batch csr-load
//            latency is removed from the dependent chain, and row loads issue
//            in batches of 8 (all indices register-resident).
//   GEMM1: wave owns 16 zcols x 64 nodes; aw1 preload issued post-gather
//            (flies during barrier wait, keeps gather-phase VGPR low).
//   GEMM2: wave owns 16 outcols x 32 nodes; W2 fragments software-pipelined.
// hb_in != hb_out (cross-block WAR hazard).
// LDS union: gather view stride 152, z view stride 280 (35,840 B).
// ---------------------------------------------------------------------------
__global__ __launch_bounds__(1024, 8) void layer_fused(
    const short* __restrict__ hb_in,
    const int* __restrict__ rowst,
    const int* __restrict__ csr,
    const short* __restrict__ W1l,    // [256][128] fp16
    const float* __restrict__ b1l,    // [256]
    const short* __restrict__ W2l,    // [128][256] fp16
    const float* __restrict__ b2l,    // [128]
    short* __restrict__ hb_out, float* __restrict__ f_out, int last)
{
    __shared__ __attribute__((aligned(16))) short sU[64 * ZS];   // 35,840 B

    const int tid = threadIdx.x;
    const int r0 = blockIdx.x * 64;
    const int wave = tid >> 6;
    const int lane = tid & 63;
    const int quad = lane >> 4;
    const int l16 = lane & 15;

    // ---- Stage A: neighbor gather, shfl-distributed indices, 8-deep loads ----
    {
        int row = tid >> 4;           // 0..63
        int ch = (tid & 15) * 8;      // 0,8,...,120
        int grow = r0 + row;
        const int gbase = lane & 48;  // 16-lane group base within wave
        half8 acc = {};
        if (grow < ND) {
            acc = __builtin_bit_cast(half8,
                *reinterpret_cast<const short8*>(&hb_in[(size_t)grow * DD + ch]));
            int s = rowst[grow], e = rowst[grow + 1];
            int deg = e - s;
            int i = s;
            while (deg > 0) {
                // one coalesced index load per 16 edges (csr padded 64B at end)
                int myidx = csr[i + (tid & 15)];
                int c = deg < 16 ? deg : 16;
                int done = 0;
                while (done < c) {
                    int cc = c - done; if (cc > 8) cc = 8;
                    half8 a[8];
                    #pragma unroll
                    for (int k = 0; k < 8; ++k) {
                        if (k < cc) {
                            int srcrow = __shfl(myidx, gbase + done + k, 64);
                            a[k] = __builtin_bit_cast(half8,
                                *reinterpret_cast<const short8*>(
                                    &hb_in[(size_t)srcrow * DD + ch]));
                        }
                    }
                    #pragma unroll
                    for (int k = 0; k < 8; ++k)
                        if (k < cc) acc = acc + a[k];
                    done += cc;
                }
                i += c; deg -= c;
            }
        }
        *reinterpret_cast<short8*>(&sU[row * GS + ch]) = __builtin_bit_cast(short8, acc);
    }

    // Preload GEMM1 weight fragments + bias (issued pre-barrier, used after)
    const int zrow = wave * 16 + l16;
    half8 aw1[4];
    for (int ks = 0; ks < 4; ++ks)
        aw1[ks] = __builtin_bit_cast(half8,
            *reinterpret_cast<const short8*>(&W1l[zrow * DD + ks * 32 + quad * 8]));
    float4 bias1 = *reinterpret_cast<const float4*>(&b1l[wave * 16 + quad * 4]);
    __syncthreads();

    // ---- GEMM1' zT = W1(A) x agg(B): wave owns zcols [wave*16,+16) x 64 nodes ----
    const f32x4 zero4 = {0.f, 0.f, 0.f, 0.f};
    f32x4 acc1[4];
    for (int nt = 0; nt < 4; ++nt) acc1[nt] = zero4;

    for (int ks = 0; ks < 4; ++ks) {
        int kofs = ks * 32 + quad * 8;
        for (int nt = 0; nt < 4; ++nt) {
            half8 bn = __builtin_bit_cast(half8,
                *reinterpret_cast<const short8*>(&sU[(nt * 16 + l16) * GS + kofs]));
            acc1[nt] = __builtin_amdgcn_mfma_f32_16x16x32_f16(aw1[ks], bn, acc1[nt], 0, 0, 0);
        }
    }
    __syncthreads();   // gather view dead; z view reuses LDS

    // ---- Stage C: bias + ReLU -> sU[node][zcol] (stride ZS), pk-f16 writes ----
    {
        int zc = wave * 16 + quad * 4;
        for (int nt = 0; nt < 4; ++nt) {
            int node = nt * 16 + l16;
            half2v p0 = pk2(fmaxf(acc1[nt][0] + bias1.x, 0.f),
                            fmaxf(acc1[nt][1] + bias1.y, 0.f));
            half2v p1 = pk2(fmaxf(acc1[nt][2] + bias1.z, 0.f),
                            fmaxf(acc1[nt][3] + bias1.w, 0.f));
            half4 hv = __builtin_shufflevector(p0, p1, 0, 1, 2, 3);
            *reinterpret_cast<short4v*>(&sU[node * ZS + zc]) = __builtin_bit_cast(short4v, hv);
        }
    }

    // Preload GEMM2 first weight fragment + bias while barrier settles
    const int ct16 = wave >> 1;
    const int nh = wave & 1;
    const int orow = ct16 * 16 + l16;
    half8 w_cur = __builtin_bit_cast(half8,
        *reinterpret_cast<const short8*>(&W2l[orow * HH + quad * 8]));
    float4 bias2 = *reinterpret_cast<const float4*>(&b2l[ct16 * 16 + quad * 4]);
    __syncthreads();

    // ---- GEMM2' hT = W2(A) x z(B): wave owns outcols [ct16*16,+16) x 32 nodes,
    //      W2 fragments software-pipelined ----
    f32x4 acc2[2];
    for (int nt = 0; nt < 2; ++nt) acc2[nt] = zero4;

    for (int ks = 0; ks < 8; ++ks) {
        half8 w_next;
        if (ks < 7)
            w_next = __builtin_bit_cast(half8,
                *reinterpret_cast<const short8*>(&W2l[orow * HH + (ks + 1) * 32 + quad * 8]));
        int kofs = ks * 32 + quad * 8;
        for (int nt = 0; nt < 2; ++nt) {
            int node = nh * 32 + nt * 16 + l16;
            half8 bn = __builtin_bit_cast(half8,
                *reinterpret_cast<const short8*>(&sU[node * ZS + kofs]));
            acc2[nt] = __builtin_amdgcn_mfma_f32_16x16x32_f16(w_cur, bn, acc2[nt], 0, 0, 0);
        }
        w_cur = w_next;
    }

    // ---- Stage E: bias (+ReLU) -> vectorized global stores ----
    {
        int oc = ct16 * 16 + quad * 4;
        for (int nt = 0; nt < 2; ++nt) {
            int node = r0 + nh * 32 + nt * 16 + l16;
            if (node < ND) {
                float v0 = acc2[nt][0] + bias2.x;
                float v1 = acc2[nt][1] + bias2.y;
                float v2 = acc2[nt][2] + bias2.z;
                float v3 = acc2[nt][3] + bias2.w;
                if (!last) {
                    half2v p0 = pk2(fmaxf(v0, 0.f), fmaxf(v1, 0.f));
                    half2v p1 = pk2(fmaxf(v2, 0.f), fmaxf(v3, 0.f));
                    half4 hv = __builtin_shufflevector(p0, p1, 0, 1, 2, 3);
                    *reinterpret_cast<short4v*>(&hb_out[(size_t)node * DD + oc]) =
                        __builtin_bit_cast(short4v, hv);
                } else {
                    float4 st; st.x = v0; st.y = v1; st.z = v2; st.w = v3;
                    *reinterpret_cast<float4*>(&f_out[(size_t)node * DD + oc]) = st;
                }
            }
        }
    }
}

extern "C" void kernel_launch(void* const* d_in, const int* in_sizes, int n_in,
                              void* d_out, int out_size, void* d_ws, size_t ws_size,
                              hipStream_t stream)
{
    const float* x  = (const float*)d_in[0];
    const int* ei   = (const int*)d_in[1];
    const int* src  = ei;
    const int* dst  = ei + EE;
    const float* W1 = (const float*)d_in[2];
    const float* b1 = (const float*)d_in[3];
    const float* g1 = (const float*)d_in[4];
    const float* bb1= (const float*)d_in[5];
    const float* m1 = (const float*)d_in[6];
    const float* v1 = (const float*)d_in[7];
    const float* W2 = (const float*)d_in[8];
    const float* b2 = (const float*)d_in[9];
    const float* g2 = (const float*)d_in[10];
    const float* bb2= (const float*)d_in[11];
    const float* m2 = (const float*)d_in[12];
    const float* v2 = (const float*)d_in[13];

    char* w = (char*)d_ws;
    short* hbufA = (short*)w;                                 // 25,600,000
    short* hbufB = (short*)(w + 25600000);                    // 25,600,000
    short* W1p   = (short*)(w + 51200000);                    //    327,680
    short* W2p   = (short*)(w + 51527680);                    //    327,680
    float* b1e   = (float*)(w + 51855360);                    //      5,120
    float* b2e   = (float*)(w + 51860480);                    //      2,560
    int*   cnt   = (int*)  (w + 51863040);                    //    400,000
    int*   cursor= (int*)  (w + 52263040);                    //    400,000 (contiguous after cnt)
    int*   rowst = (int*)  (w + 52663040);                    //    400,032
    int*   csr   = (int*)  (w + 53063072);                    //  2,560,000 (+64B overread pad)
    int*   bsum  = (int*)  (w + 55623136);                    //      1,664
    float* out   = (float*)d_out;

    // zero cnt + cursor (contiguous 800,000 B) — capture-safe async memset
    (void)hipMemsetAsync(cnt, 0, 800000, stream);
    setup<<<15640, 256, 0, stream>>>(W1, b1, g1, bb1, m1, v1,
                                     W2, b2, g2, bb2, m2, v2,
                                     x, dst, W1p, b1e, W2p, b2e, hbufA, cnt);
    scan_block<<<391, 256, 0, stream>>>(cnt, bsum);
    apply_offs2<<<391, 256, 0, stream>>>(cnt, bsum, rowst);
    fill_csr<<<2500, 256, 0, stream>>>(src, dst, rowst, cursor, csr);

    short* hin = hbufA;
    short* hout = hbufB;
    for (int l = 0; l < LL; ++l) {
        layer_fused<<<1563, 1024, 0, stream>>>(hin, rowst, csr,
                                               W1p + l * 32768, b1e + l * HH,
                                               W2p + l * 32768, b2e + l * DD,
                                               hout, out, (l == LL - 1) ? 1 : 0);
        short* t = hin; hin = hout; hout = t;
    }
}